// Round 1
// baseline (677.744 us; speedup 1.0000x reference)
//
#include <hip/hip_runtime.h>

#define HBV_T    2000
#define HBV_B    1024
#define HBV_LENF 15
#define HBV_NZ   1e-5f

// One thread per (grid_cell b, component m) chain. 16384 threads total.
// Lane layout: lane = (b%4)*16 + m  ->  16-lane shfl_xor tree reduces over m.
// FIR routing fused via 15-deep register shift buffer (time loop unrolled by 15
// so all indices are compile-time constants -> stays in VGPRs).

#define HBV_STEP(ii, Pm, Tc, PETm) do {                                        \
    float rain = ((Tc) >= parTT) ? (Pm) : 0.0f;                                \
    float snow = (Pm) - rain; /* exact complement of rain */                   \
    SNOWPACK += snow;                                                          \
    float melt = fminf(fmaxf(parCFMAX * ((Tc) - parTT), 0.0f), SNOWPACK);      \
    MELTWATER += melt; SNOWPACK -= melt;                                       \
    float refreeze = fminf(fmaxf(CFRC * (parTT - (Tc)), 0.0f), MELTWATER);     \
    SNOWPACK += refreeze; MELTWATER -= refreeze;                               \
    float tosoil = fmaxf(MELTWATER - parCWH * SNOWPACK, 0.0f);                 \
    MELTWATER -= tosoil;                                                       \
    float sw = fminf(__builtin_amdgcn_exp2f(                                   \
                       parBETA * __builtin_amdgcn_logf(SM * invFC)), 1.0f);    \
    float rt = rain + tosoil;                                                  \
    float recharge = rt * sw;                                                  \
    SM += rt - recharge;                                                       \
    float excess = fmaxf(SM - parFC, 0.0f);                                    \
    SM -= excess;                                                              \
    float capillary = fminf(SLZ, parC * SLZ * (1.0f - fminf(SM * invFC, 1.0f)));\
    SM += capillary; SLZ -= capillary;                                         \
    float ef = __builtin_amdgcn_exp2f(                                         \
        parBETAET * __builtin_amdgcn_logf(fminf(SM * invLPFC, 1.0f)));         \
    float ETact = fminf((PETm) * ef, SM);                                      \
    SM = fmaxf(SM - ETact, HBV_NZ);                                            \
    SUZ += recharge + excess;                                                  \
    float PERCa = fminf(SUZ, parPERC);                                         \
    SUZ -= PERCa;                                                              \
    float Q0 = parK0 * fmaxf(SUZ - parUZL, 0.0f);                              \
    SUZ -= Q0;                                                                 \
    float Q1 = parK1 * SUZ;                                                    \
    SUZ -= Q1;                                                                 \
    SLZ += PERCa;                                                              \
    float Q2 = parK2 * SLZ;                                                    \
    SLZ -= Q2;                                                                 \
    q[(ii) % HBV_LENF] = Q0 + Q1 + Q2;                                         \
    float qr = 0.0f;                                                           \
    _Pragma("unroll")                                                          \
    for (int k_ = 0; k_ < HBV_LENF; ++k_)                                      \
        qr += w[k_] * q[((ii) - k_ + HBV_LENF) % HBV_LENF];                    \
    qr += __shfl_xor(qr, 1);                                                   \
    qr += __shfl_xor(qr, 2);                                                   \
    qr += __shfl_xor(qr, 4);                                                   \
    qr += __shfl_xor(qr, 8);                                                   \
    if (m == 0) out[(size_t)t * HBV_B + b] = qr;                               \
    ++t;                                                                       \
} while (0)

__global__ __launch_bounds__(64, 1)
void hbv_fused_kernel(const float* __restrict__ x_phy,   // (2000, 1024, 3)
                      const float* __restrict__ ps,      // (1024, 288)
                      float* __restrict__ out)           // (2000, 1024)
{
    const int tid = blockIdx.x * 64 + (int)threadIdx.x;  // 0..16383
    const int b = tid >> 4;
    const int m = tid & 15;

    const float* __restrict__ pb = ps + (size_t)b * 288;

    // physical params, scaled to bounds (parRT/parAC are unused by forward)
    const float parBETA   = 1.0f   + pb[ 0*16 + m] * 5.0f;
    const float parFC     = 50.0f  + pb[ 1*16 + m] * 950.0f;
    const float parK0     = 0.05f  + pb[ 2*16 + m] * 0.85f;
    const float parK1     = 0.01f  + pb[ 3*16 + m] * 0.49f;
    const float parK2     = 0.001f + pb[ 4*16 + m] * 0.199f;
    const float parLP     = 0.2f   + pb[ 5*16 + m] * 0.8f;
    const float parPERC   =          pb[ 6*16 + m] * 10.0f;
    const float parUZL    =          pb[ 7*16 + m] * 100.0f;
    const float parTT     = -2.5f  + pb[ 8*16 + m] * 5.0f;
    const float parCFMAX  = 0.5f   + pb[ 9*16 + m] * 9.5f;
    const float parCFR    =          pb[10*16 + m] * 0.1f;
    const float parCWH    =          pb[11*16 + m] * 0.2f;
    const float parBETAET = 0.3f   + pb[12*16 + m] * 4.7f;
    const float parC      =          pb[13*16 + m];
    const float rout_a    =          pb[256 + m]      * 2.9f;
    const float rout_b    =          pb[256 + 16 + m] * 6.5f;

    const float CFRC    = parCFR * parCFMAX;
    const float invFC   = 1.0f / parFC;
    const float invLPFC = 1.0f / (parLP * parFC);

    // Routing weights. The 1/(Gamma(a)*theta^a) factor cancels under
    // normalization, so no lgamma is needed:
    //   w[k] ∝ t_k^(a-1) * exp(-t_k/theta),  t_k = k+0.5
    // Pre-scaled by 1/16 to fold in the mean over NMUL.
    const float aa    = fmaxf(rout_a, 0.0f) + 0.1f;
    const float theta = fmaxf(rout_b, 0.0f) + 0.5f;
    const float am1   = aa - 1.0f;
    const float nit   = -1.4426950408889634f / theta;  // -log2(e)/theta
    float w[HBV_LENF];
    float wsum = 0.0f;
#pragma unroll
    for (int k = 0; k < HBV_LENF; ++k) {
        float tk = (float)k + 0.5f;
        float e  = am1 * __builtin_amdgcn_logf(tk) + nit * tk;  // log2-domain
        w[k] = __builtin_amdgcn_exp2f(e);
        wsum += w[k];
    }
    const float wscale = 1.0f / (16.0f * wsum);
#pragma unroll
    for (int k = 0; k < HBV_LENF; ++k) w[k] *= wscale;

    // state
    float SNOWPACK = HBV_NZ, MELTWATER = HBV_NZ, SM = HBV_NZ,
          SUZ = HBV_NZ, SLZ = HBV_NZ;
    float q[HBV_LENF];
#pragma unroll
    for (int k = 0; k < HBV_LENF; ++k) q[k] = 0.0f;

    const float* __restrict__ xb = x_phy + (size_t)b * 3;  // + t*3072 per step

    int t = 0;
    // 2000 = 133*15 + 5 ; 1995 % 15 == 0 so the remainder chunk's static
    // circular-buffer indices (0..4) continue the sequence correctly.
#pragma unroll 1
    for (int c = 0; c < 133; ++c) {
        float Pf[15], Tf[15], Ef[15];
#pragma unroll
        for (int k = 0; k < 15; ++k) {   // bulk prefetch: 45 dwords, one wait
            const float* p = xb + (size_t)(t + k) * (HBV_B * 3);
            Pf[k] = p[0]; Tf[k] = p[1]; Ef[k] = p[2];
        }
        HBV_STEP( 0, Pf[ 0], Tf[ 0], Ef[ 0]);
        HBV_STEP( 1, Pf[ 1], Tf[ 1], Ef[ 1]);
        HBV_STEP( 2, Pf[ 2], Tf[ 2], Ef[ 2]);
        HBV_STEP( 3, Pf[ 3], Tf[ 3], Ef[ 3]);
        HBV_STEP( 4, Pf[ 4], Tf[ 4], Ef[ 4]);
        HBV_STEP( 5, Pf[ 5], Tf[ 5], Ef[ 5]);
        HBV_STEP( 6, Pf[ 6], Tf[ 6], Ef[ 6]);
        HBV_STEP( 7, Pf[ 7], Tf[ 7], Ef[ 7]);
        HBV_STEP( 8, Pf[ 8], Tf[ 8], Ef[ 8]);
        HBV_STEP( 9, Pf[ 9], Tf[ 9], Ef[ 9]);
        HBV_STEP(10, Pf[10], Tf[10], Ef[10]);
        HBV_STEP(11, Pf[11], Tf[11], Ef[11]);
        HBV_STEP(12, Pf[12], Tf[12], Ef[12]);
        HBV_STEP(13, Pf[13], Tf[13], Ef[13]);
        HBV_STEP(14, Pf[14], Tf[14], Ef[14]);
    }
    {   // remainder: 5 steps
        float Pf[5], Tf[5], Ef[5];
#pragma unroll
        for (int k = 0; k < 5; ++k) {
            const float* p = xb + (size_t)(t + k) * (HBV_B * 3);
            Pf[k] = p[0]; Tf[k] = p[1]; Ef[k] = p[2];
        }
        HBV_STEP(0, Pf[0], Tf[0], Ef[0]);
        HBV_STEP(1, Pf[1], Tf[1], Ef[1]);
        HBV_STEP(2, Pf[2], Tf[2], Ef[2]);
        HBV_STEP(3, Pf[3], Tf[3], Ef[3]);
        HBV_STEP(4, Pf[4], Tf[4], Ef[4]);
    }
}

extern "C" void kernel_launch(void* const* d_in, const int* in_sizes, int n_in,
                              void* d_out, int out_size, void* d_ws, size_t ws_size,
                              hipStream_t stream) {
    const float* x_phy = (const float*)d_in[0];   // (2000,1024,3) fp32
    const float* ps    = (const float*)d_in[1];   // (1024,288)    fp32
    float* out         = (float*)d_out;           // (2000,1024)   fp32

    // 16384 chains -> 256 blocks x 64 threads: 1 wave per CU, each wave on its
    // own SIMD (structural parallelism ceiling: 256 waves / 1024 SIMDs).
    hbv_fused_kernel<<<256, 64, 0, stream>>>(x_phy, ps, out);
}

// Round 2
// 450.803 us; speedup vs baseline: 1.5034x; 1.5034x over previous
//
#include <hip/hip_runtime.h>

#define HBV_B    1024
#define HBV_LENF 15
#define HBV_NZ   1e-5f

// ---------------------------------------------------------------------------
// One thread per (grid_cell b, component m) chain; 16384 threads, 256 waves.
// Wall time is dictated by ONE wave's in-order 2000-step serial stream, so
// every optimization targets stream length / stall cycles:
//   - FIR routing fused via 15-deep register ring (loop unrolled by 15).
//   - 16-lane mean over m via DPP row_ror butterfly (VALU latency, no LDS).
//   - Forcing loads double-buffered: prefetch chunk c+1 during chunk c.
// ---------------------------------------------------------------------------

// qr += lane-rotated qr within the 16-lane DPP row (m-group).
// row_ror:N ctrl = 0x120 + N. bound_ctrl=1, full row/bank masks.
#define DPP_ADD_ROR(x, ctrl) do {                                              \
    int _r = __builtin_amdgcn_update_dpp(0, __float_as_int(x),                 \
                                         (ctrl), 0xF, 0xF, true);              \
    (x) += __int_as_float(_r);                                                 \
} while (0)

#define HBV_STEP(ii, Pm, Tc, PETm) do {                                        \
    float rain = ((Tc) >= parTT) ? (Pm) : 0.0f;                                \
    float snow = (Pm) - rain; /* exact complement */                           \
    SNOWPACK += snow;                                                          \
    float melt = fminf(fmaxf(__builtin_fmaf(parCFMAX, (Tc), negCT), 0.0f),     \
                       SNOWPACK);                                              \
    MELTWATER += melt; SNOWPACK -= melt;                                       \
    float refreeze = fminf(fmaxf(__builtin_fmaf(-CFRC, (Tc), CFRCTT), 0.0f),   \
                           MELTWATER);                                         \
    SNOWPACK += refreeze; MELTWATER -= refreeze;                               \
    float tosoil = fmaxf(__builtin_fmaf(-parCWH, SNOWPACK, MELTWATER), 0.0f);  \
    MELTWATER -= tosoil;                                                       \
    float sw = fminf(__builtin_amdgcn_exp2f(                                   \
                       parBETA * __builtin_amdgcn_logf(SM * invFC)), 1.0f);    \
    float rt = rain + tosoil;                                                  \
    float recharge = rt * sw;                                                  \
    SM += rt - recharge;                                                       \
    float excess = fmaxf(SM - parFC, 0.0f);                                    \
    SM -= excess;                                                              \
    float capillary = fminf(SLZ, parC * SLZ * (1.0f - fminf(SM * invFC, 1.0f)));\
    SM += capillary; SLZ -= capillary;                                         \
    float ef = __builtin_amdgcn_exp2f(                                         \
        parBETAET * __builtin_amdgcn_logf(fminf(SM * invLPFC, 1.0f)));         \
    float ETact = fminf((PETm) * ef, SM);                                      \
    SM = fmaxf(SM - ETact, HBV_NZ);                                            \
    SUZ += recharge + excess;                                                  \
    float PERCa = fminf(SUZ, parPERC);                                         \
    SUZ -= PERCa;                                                              \
    float Q0 = parK0 * fmaxf(SUZ - parUZL, 0.0f);                              \
    SUZ -= Q0;                                                                 \
    float Q1 = parK1 * SUZ;                                                    \
    SUZ -= Q1;                                                                 \
    SLZ += PERCa;                                                              \
    float Q2 = parK2 * SLZ;                                                    \
    SLZ -= Q2;                                                                 \
    q[(ii) % HBV_LENF] = Q0 + Q1 + Q2;                                         \
    float qr = 0.0f;                                                           \
    _Pragma("unroll")                                                          \
    for (int k_ = 0; k_ < HBV_LENF; ++k_)                                      \
        qr += w[k_] * q[((ii) - k_ + HBV_LENF) % HBV_LENF];                    \
    /* 16-lane sum over m via DPP row_ror butterfly (no LDS round trips) */    \
    DPP_ADD_ROR(qr, 0x128);  /* row_ror:8 */                                   \
    DPP_ADD_ROR(qr, 0x124);  /* row_ror:4 */                                   \
    DPP_ADD_ROR(qr, 0x122);  /* row_ror:2 */                                   \
    DPP_ADD_ROR(qr, 0x121);  /* row_ror:1 */                                   \
    if (m == 0) out[(size_t)t * HBV_B + b] = qr;                               \
    ++t;                                                                       \
} while (0)

#define LOAD_CHUNK(Pf, Tf, Ef, tbase) do {                                     \
    _Pragma("unroll")                                                          \
    for (int k_ = 0; k_ < 15; ++k_) {                                          \
        const float* _p = xb + (size_t)((tbase) + k_) * (HBV_B * 3);           \
        (Pf)[k_] = _p[0]; (Tf)[k_] = _p[1]; (Ef)[k_] = _p[2];                  \
    }                                                                          \
} while (0)

#define RUN15(Pf, Tf, Ef) do {                                                 \
    HBV_STEP( 0, (Pf)[ 0], (Tf)[ 0], (Ef)[ 0]);                                \
    HBV_STEP( 1, (Pf)[ 1], (Tf)[ 1], (Ef)[ 1]);                                \
    HBV_STEP( 2, (Pf)[ 2], (Tf)[ 2], (Ef)[ 2]);                                \
    HBV_STEP( 3, (Pf)[ 3], (Tf)[ 3], (Ef)[ 3]);                                \
    HBV_STEP( 4, (Pf)[ 4], (Tf)[ 4], (Ef)[ 4]);                                \
    HBV_STEP( 5, (Pf)[ 5], (Tf)[ 5], (Ef)[ 5]);                                \
    HBV_STEP( 6, (Pf)[ 6], (Tf)[ 6], (Ef)[ 6]);                                \
    HBV_STEP( 7, (Pf)[ 7], (Tf)[ 7], (Ef)[ 7]);                                \
    HBV_STEP( 8, (Pf)[ 8], (Tf)[ 8], (Ef)[ 8]);                                \
    HBV_STEP( 9, (Pf)[ 9], (Tf)[ 9], (Ef)[ 9]);                                \
    HBV_STEP(10, (Pf)[10], (Tf)[10], (Ef)[10]);                                \
    HBV_STEP(11, (Pf)[11], (Tf)[11], (Ef)[11]);                                \
    HBV_STEP(12, (Pf)[12], (Tf)[12], (Ef)[12]);                                \
    HBV_STEP(13, (Pf)[13], (Tf)[13], (Ef)[13]);                                \
    HBV_STEP(14, (Pf)[14], (Tf)[14], (Ef)[14]);                                \
} while (0)

__global__ __launch_bounds__(64, 1)
void hbv_fused_kernel(const float* __restrict__ x_phy,   // (2000, 1024, 3)
                      const float* __restrict__ ps,      // (1024, 288)
                      float* __restrict__ out)           // (2000, 1024)
{
    const int tid = blockIdx.x * 64 + (int)threadIdx.x;  // 0..16383
    const int b = tid >> 4;
    const int m = tid & 15;

    const float* __restrict__ pb = ps + (size_t)b * 288;

    // physical params scaled to bounds (parRT/parAC unused by forward)
    const float parBETA   = 1.0f   + pb[ 0*16 + m] * 5.0f;
    const float parFC     = 50.0f  + pb[ 1*16 + m] * 950.0f;
    const float parK0     = 0.05f  + pb[ 2*16 + m] * 0.85f;
    const float parK1     = 0.01f  + pb[ 3*16 + m] * 0.49f;
    const float parK2     = 0.001f + pb[ 4*16 + m] * 0.199f;
    const float parLP     = 0.2f   + pb[ 5*16 + m] * 0.8f;
    const float parPERC   =          pb[ 6*16 + m] * 10.0f;
    const float parUZL    =          pb[ 7*16 + m] * 100.0f;
    const float parTT     = -2.5f  + pb[ 8*16 + m] * 5.0f;
    const float parCFMAX  = 0.5f   + pb[ 9*16 + m] * 9.5f;
    const float parCFR    =          pb[10*16 + m] * 0.1f;
    const float parCWH    =          pb[11*16 + m] * 0.2f;
    const float parBETAET = 0.3f   + pb[12*16 + m] * 4.7f;
    const float parC      =          pb[13*16 + m];
    const float rout_a    =          pb[256 + m]      * 2.9f;
    const float rout_b    =          pb[256 + 16 + m] * 6.5f;

    const float CFRC    = parCFR * parCFMAX;
    const float invFC   = 1.0f / parFC;
    const float invLPFC = 1.0f / (parLP * parFC);
    const float negCT   = -parCFMAX * parTT;   // melt     = fma(CFMAX, Tc, negCT)
    const float CFRCTT  =  CFRC * parTT;       // refreeze = fma(-CFRC, Tc, CFRCTT)

    // Routing weights: 1/(Gamma(a)*theta^a) cancels under normalization,
    // so w[k] ∝ t_k^(a-1) * exp(-t_k/theta). Pre-scaled by 1/16 (mean over m).
    const float aa    = fmaxf(rout_a, 0.0f) + 0.1f;
    const float theta = fmaxf(rout_b, 0.0f) + 0.5f;
    const float am1   = aa - 1.0f;
    const float nit   = -1.4426950408889634f / theta;  // -log2(e)/theta
    float w[HBV_LENF];
    float wsum = 0.0f;
#pragma unroll
    for (int k = 0; k < HBV_LENF; ++k) {
        float tk = (float)k + 0.5f;
        float e  = am1 * __builtin_amdgcn_logf(tk) + nit * tk;  // log2-domain
        w[k] = __builtin_amdgcn_exp2f(e);
        wsum += w[k];
    }
    const float wscale = 1.0f / (16.0f * wsum);
#pragma unroll
    for (int k = 0; k < HBV_LENF; ++k) w[k] *= wscale;

    // state
    float SNOWPACK = HBV_NZ, MELTWATER = HBV_NZ, SM = HBV_NZ,
          SUZ = HBV_NZ, SLZ = HBV_NZ;
    float q[HBV_LENF];
#pragma unroll
    for (int k = 0; k < HBV_LENF; ++k) q[k] = 0.0f;

    const float* __restrict__ xb = x_phy + (size_t)b * 3;

    // Time layout: 133 full 15-step chunks (t 0..1994) + 5-step tail.
    // 1995 % 15 == 0, so the tail's static ring indices (0..4) continue
    // the circular q-buffer correctly.
    float Pa[15], Ta[15], Ea[15], Pb[15], Tb[15], Eb[15];

    int t = 0;
    LOAD_CHUNK(Pa, Ta, Ea, 0);

    // Software pipeline, 2 chunks per iteration: prefetch next chunk's 45
    // forcing dwords while the current chunk's 15 steps execute — the vmcnt
    // wait lands ~15 steps after issue instead of immediately.
#pragma unroll 1
    for (int j = 0; j < 66; ++j) {            // chunks 0..131
        LOAD_CHUNK(Pb, Tb, Eb, 15 * (2 * j + 1));
        RUN15(Pa, Ta, Ea);
        LOAD_CHUNK(Pa, Ta, Ea, 15 * (2 * j + 2));
        RUN15(Pb, Tb, Eb);
    }
    // chunk 132 already resident in A (loaded at j=65); prefetch the tail.
    {
#pragma unroll
        for (int k = 0; k < 5; ++k) {
            const float* p = xb + (size_t)(1995 + k) * (HBV_B * 3);
            Pb[k] = p[0]; Tb[k] = p[1]; Eb[k] = p[2];
        }
        RUN15(Pa, Ta, Ea);                    // t -> 1995
        HBV_STEP(0, Pb[0], Tb[0], Eb[0]);
        HBV_STEP(1, Pb[1], Tb[1], Eb[1]);
        HBV_STEP(2, Pb[2], Tb[2], Eb[2]);
        HBV_STEP(3, Pb[3], Tb[3], Eb[3]);
        HBV_STEP(4, Pb[4], Tb[4], Eb[4]);
    }
}

extern "C" void kernel_launch(void* const* d_in, const int* in_sizes, int n_in,
                              void* d_out, int out_size, void* d_ws, size_t ws_size,
                              hipStream_t stream) {
    const float* x_phy = (const float*)d_in[0];   // (2000,1024,3) fp32
    const float* ps    = (const float*)d_in[1];   // (1024,288)    fp32
    float* out         = (float*)d_out;           // (2000,1024)   fp32

    // 16384 chains -> 256 blocks x 64 threads: 1 wave per CU. Wall time is
    // set by one wave's serial stream, not occupancy.
    hbv_fused_kernel<<<256, 64, 0, stream>>>(x_phy, ps, out);
}

// Round 3
// 393.788 us; speedup vs baseline: 1.7211x; 1.1448x over previous
//
#include <hip/hip_runtime.h>

#define HBV_B    1024
#define HBV_NZ   1e-5f
#define LDSTR    64            // floats per step slot in LDS (one per lane)
#define BUFSZ    (15 * LDSTR)  // one 15-step chunk buffer

// ---------------------------------------------------------------------------
// Producer/consumer wave split, one block = 2 waves on 2 SIMDs of one CU.
//   wave 0 (producer): the serial 2000-step HBV recurrence — ONLY the 5-state
//     update; Qsim goes to LDS (1 ds_write/step). This wave's in-order stream
//     sets wall time, so it carries nothing else.
//   wave 1 (consumer): FIR routing (15-tap gamma kernel, register ring),
//     16-lane DPP mean over m, global store. ~4x under-loaded -> fully hidden.
// Chunked hand-over: 15 steps per chunk, double-buffered LDS, one s_barrier
// per chunk (134 total). Producer writes buf[j&1] while consumer reads
// buf[(j-1)&1].
// ---------------------------------------------------------------------------

struct F3 { float x, y, z; };   // 12B forcing record (P, T, PET)

// qr += lane-rotated qr within the 16-lane DPP row (row_ror:N = 0x120+N).
#define DPP_ADD_ROR(x, ctrl) do {                                              \
    int _r = __builtin_amdgcn_update_dpp(0, __float_as_int(x),                 \
                                         (ctrl), 0xF, 0xF, true);              \
    (x) += __int_as_float(_r);                                                 \
} while (0)

// ---- producer: one HBV state step; Qsim -> LDS ----------------------------
#define HBV_PSTEP(s, Pm, Tc, PETm, qdst) do {                                  \
    float rain = ((Tc) >= parTT) ? (Pm) : 0.0f;                                \
    float snow = (Pm) - rain;                                                  \
    SNOWPACK += snow;                                                          \
    float melt = fminf(fmaxf(__builtin_fmaf(parCFMAX, (Tc), negCT), 0.0f),     \
                       SNOWPACK);                                              \
    MELTWATER += melt; SNOWPACK -= melt;                                       \
    float refreeze = fminf(fmaxf(__builtin_fmaf(-CFRC, (Tc), CFRCTT), 0.0f),   \
                           MELTWATER);                                         \
    SNOWPACK += refreeze; MELTWATER -= refreeze;                               \
    float tosoil = fmaxf(__builtin_fmaf(-parCWH, SNOWPACK, MELTWATER), 0.0f);  \
    MELTWATER -= tosoil;                                                       \
    float sw = fminf(__builtin_amdgcn_exp2f(                                   \
                       parBETA * __builtin_amdgcn_logf(SM * invFC)), 1.0f);    \
    float rt = rain + tosoil;                                                  \
    float recharge = rt * sw;                                                  \
    SM += rt - recharge;                                                       \
    float excess = fmaxf(SM - parFC, 0.0f);                                    \
    SM -= excess;                                                              \
    float capillary = fminf(SLZ, parC * SLZ * (1.0f - fminf(SM * invFC, 1.0f)));\
    SM += capillary; SLZ -= capillary;                                         \
    float ef = __builtin_amdgcn_exp2f(                                         \
        parBETAET * __builtin_amdgcn_logf(fminf(SM * invLPFC, 1.0f)));         \
    float ETact = fminf((PETm) * ef, SM);                                      \
    SM = fmaxf(SM - ETact, HBV_NZ);                                            \
    SUZ += recharge + excess;                                                  \
    float PERCa = fminf(SUZ, parPERC);                                         \
    SUZ -= PERCa;                                                              \
    float Q0 = parK0 * fmaxf(SUZ - parUZL, 0.0f);                              \
    SUZ -= Q0;                                                                 \
    float Q1 = parK1 * SUZ;                                                    \
    SUZ -= Q1;                                                                 \
    SLZ += PERCa;                                                              \
    float Q2 = parK2 * SLZ;                                                    \
    SLZ -= Q2;                                                                 \
    (qdst)[(s) * LDSTR] = Q0 + Q1 + Q2;                                        \
} while (0)

#define RUN15P(Pf, Tf, Ef, qdst) do {                                          \
    HBV_PSTEP( 0, (Pf)[ 0], (Tf)[ 0], (Ef)[ 0], qdst);                         \
    HBV_PSTEP( 1, (Pf)[ 1], (Tf)[ 1], (Ef)[ 1], qdst);                         \
    HBV_PSTEP( 2, (Pf)[ 2], (Tf)[ 2], (Ef)[ 2], qdst);                         \
    HBV_PSTEP( 3, (Pf)[ 3], (Tf)[ 3], (Ef)[ 3], qdst);                         \
    HBV_PSTEP( 4, (Pf)[ 4], (Tf)[ 4], (Ef)[ 4], qdst);                         \
    HBV_PSTEP( 5, (Pf)[ 5], (Tf)[ 5], (Ef)[ 5], qdst);                         \
    HBV_PSTEP( 6, (Pf)[ 6], (Tf)[ 6], (Ef)[ 6], qdst);                         \
    HBV_PSTEP( 7, (Pf)[ 7], (Tf)[ 7], (Ef)[ 7], qdst);                         \
    HBV_PSTEP( 8, (Pf)[ 8], (Tf)[ 8], (Ef)[ 8], qdst);                         \
    HBV_PSTEP( 9, (Pf)[ 9], (Tf)[ 9], (Ef)[ 9], qdst);                         \
    HBV_PSTEP(10, (Pf)[10], (Tf)[10], (Ef)[10], qdst);                         \
    HBV_PSTEP(11, (Pf)[11], (Tf)[11], (Ef)[11], qdst);                         \
    HBV_PSTEP(12, (Pf)[12], (Tf)[12], (Ef)[12], qdst);                         \
    HBV_PSTEP(13, (Pf)[13], (Tf)[13], (Ef)[13], qdst);                         \
    HBV_PSTEP(14, (Pf)[14], (Tf)[14], (Ef)[14], qdst);                         \
} while (0)

#define LOAD_CHUNK15(Pf, Tf, Ef, tbase) do {                                   \
    _Pragma("unroll")                                                          \
    for (int k_ = 0; k_ < 15; ++k_) {                                          \
        F3 _f = xb3[(size_t)((tbase) + k_) * HBV_B];                           \
        (Pf)[k_] = _f.x; (Tf)[k_] = _f.y; (Ef)[k_] = _f.z;                     \
    }                                                                          \
} while (0)

// ---- consumer: LDS read -> 15-tap FIR (register ring) -> DPP mean -> store -
// Chunk bases are multiples of 15, so ring slot for step s is exactly s.
#define HBV_CSTEP(s, qsrc, tb) do {                                            \
    q[(s)] = (qsrc)[(s) * LDSTR];                                              \
    float qr = 0.0f;                                                           \
    _Pragma("unroll")                                                          \
    for (int k_ = 0; k_ < 15; ++k_)                                            \
        qr += w[k_] * q[((s) - k_ + 15) % 15];                                 \
    DPP_ADD_ROR(qr, 0x128);                                                    \
    DPP_ADD_ROR(qr, 0x124);                                                    \
    DPP_ADD_ROR(qr, 0x122);                                                    \
    DPP_ADD_ROR(qr, 0x121);                                                    \
    if (m == 0) out[(size_t)((tb) + (s)) * HBV_B + b] = qr;                    \
} while (0)

#define CONS15(qsrc, tb) do {                                                  \
    HBV_CSTEP( 0, qsrc, tb); HBV_CSTEP( 1, qsrc, tb); HBV_CSTEP( 2, qsrc, tb); \
    HBV_CSTEP( 3, qsrc, tb); HBV_CSTEP( 4, qsrc, tb); HBV_CSTEP( 5, qsrc, tb); \
    HBV_CSTEP( 6, qsrc, tb); HBV_CSTEP( 7, qsrc, tb); HBV_CSTEP( 8, qsrc, tb); \
    HBV_CSTEP( 9, qsrc, tb); HBV_CSTEP(10, qsrc, tb); HBV_CSTEP(11, qsrc, tb); \
    HBV_CSTEP(12, qsrc, tb); HBV_CSTEP(13, qsrc, tb); HBV_CSTEP(14, qsrc, tb); \
} while (0)

__global__ __launch_bounds__(128, 1)
void hbv_pc_kernel(const float* __restrict__ x_phy,   // (2000, 1024, 3)
                   const float* __restrict__ ps,      // (1024, 288)
                   float* __restrict__ out)           // (2000, 1024)
{
    const int lane = (int)threadIdx.x & 63;
    const int wave = (int)threadIdx.x >> 6;
    const int b = blockIdx.x * 4 + (lane >> 4);
    const int m = lane & 15;

    __shared__ float qbuf[2 * BUFSZ];   // 7.5 KB, double-buffered chunks

    const float* __restrict__ pb = ps + (size_t)b * 288;

    if (wave == 0) {
        // ------------------------- PRODUCER --------------------------------
        const float parBETA   = 1.0f   + pb[ 0*16 + m] * 5.0f;
        const float parFC     = 50.0f  + pb[ 1*16 + m] * 950.0f;
        const float parK0     = 0.05f  + pb[ 2*16 + m] * 0.85f;
        const float parK1     = 0.01f  + pb[ 3*16 + m] * 0.49f;
        const float parK2     = 0.001f + pb[ 4*16 + m] * 0.199f;
        const float parLP     = 0.2f   + pb[ 5*16 + m] * 0.8f;
        const float parPERC   =          pb[ 6*16 + m] * 10.0f;
        const float parUZL    =          pb[ 7*16 + m] * 100.0f;
        const float parTT     = -2.5f  + pb[ 8*16 + m] * 5.0f;
        const float parCFMAX  = 0.5f   + pb[ 9*16 + m] * 9.5f;
        const float parCFR    =          pb[10*16 + m] * 0.1f;
        const float parCWH    =          pb[11*16 + m] * 0.2f;
        const float parBETAET = 0.3f   + pb[12*16 + m] * 4.7f;
        const float parC      =          pb[13*16 + m];

        const float CFRC    = parCFR * parCFMAX;
        const float invFC   = 1.0f / parFC;
        const float invLPFC = 1.0f / (parLP * parFC);
        const float negCT   = -parCFMAX * parTT;
        const float CFRCTT  =  CFRC * parTT;

        float SNOWPACK = HBV_NZ, MELTWATER = HBV_NZ, SM = HBV_NZ,
              SUZ = HBV_NZ, SLZ = HBV_NZ;

        const F3* __restrict__ xb3 = (const F3*)x_phy + b;
        float* const ql0 = &qbuf[lane];
        float* const ql1 = &qbuf[BUFSZ + lane];

        float Pa[15], Ta[15], Ea[15], Pb_[15], Tb_[15], Eb_[15];
        LOAD_CHUNK15(Pa, Ta, Ea, 0);

        // chunks 0..131 as pairs; prefetch next chunk during current's steps
#pragma unroll 1
        for (int jj = 0; jj < 66; ++jj) {
            LOAD_CHUNK15(Pb_, Tb_, Eb_, 15 * (2 * jj + 1));
            RUN15P(Pa, Ta, Ea, ql0);
            __syncthreads();                       // chunk 2jj ready
            LOAD_CHUNK15(Pa, Ta, Ea, 15 * (2 * jj + 2));   // jj=65 -> c132
            RUN15P(Pb_, Tb_, Eb_, ql1);
            __syncthreads();                       // chunk 2jj+1 ready
        }
        // epilogue: chunk 132 (in A) + 5-step tail chunk 133
        {
#pragma unroll
            for (int k = 0; k < 5; ++k) {
                F3 f = xb3[(size_t)(1995 + k) * HBV_B];
                Pb_[k] = f.x; Tb_[k] = f.y; Eb_[k] = f.z;
            }
            RUN15P(Pa, Ta, Ea, ql0);
            __syncthreads();                       // chunk 132 ready
            HBV_PSTEP(0, Pb_[0], Tb_[0], Eb_[0], ql1);
            HBV_PSTEP(1, Pb_[1], Tb_[1], Eb_[1], ql1);
            HBV_PSTEP(2, Pb_[2], Tb_[2], Eb_[2], ql1);
            HBV_PSTEP(3, Pb_[3], Tb_[3], Eb_[3], ql1);
            HBV_PSTEP(4, Pb_[4], Tb_[4], Eb_[4], ql1);
            __syncthreads();                       // tail ready
        }
    } else {
        // ------------------------- CONSUMER --------------------------------
        const float rout_a = pb[256 + m]      * 2.9f;
        const float rout_b = pb[256 + 16 + m] * 6.5f;

        // w[k] ∝ t_k^(a-1) * exp(-t_k/theta); Gamma/theta^a factor cancels
        // under normalization. Pre-scaled by 1/16 to fold in the mean over m.
        const float aa    = fmaxf(rout_a, 0.0f) + 0.1f;
        const float theta = fmaxf(rout_b, 0.0f) + 0.5f;
        const float am1   = aa - 1.0f;
        const float nit   = -1.4426950408889634f / theta;
        float w[15];
        float wsum = 0.0f;
#pragma unroll
        for (int k = 0; k < 15; ++k) {
            float tk = (float)k + 0.5f;
            float e  = am1 * __builtin_amdgcn_logf(tk) + nit * tk;
            w[k] = __builtin_amdgcn_exp2f(e);
            wsum += w[k];
        }
        const float wscale = 1.0f / (16.0f * wsum);
#pragma unroll
        for (int k = 0; k < 15; ++k) w[k] *= wscale;

        float q[15];
#pragma unroll
        for (int k = 0; k < 15; ++k) q[k] = 0.0f;

        const float* const qr0 = &qbuf[lane];
        const float* const qr1 = &qbuf[BUFSZ + lane];

#pragma unroll 1
        for (int jj = 0; jj < 66; ++jj) {
            __syncthreads();
            CONS15(qr0, 30 * jj);
            __syncthreads();
            CONS15(qr1, 30 * jj + 15);
        }
        __syncthreads();
        CONS15(qr0, 1980);
        __syncthreads();
        HBV_CSTEP(0, qr1, 1995);
        HBV_CSTEP(1, qr1, 1995);
        HBV_CSTEP(2, qr1, 1995);
        HBV_CSTEP(3, qr1, 1995);
        HBV_CSTEP(4, qr1, 1995);
    }
}

extern "C" void kernel_launch(void* const* d_in, const int* in_sizes, int n_in,
                              void* d_out, int out_size, void* d_ws, size_t ws_size,
                              hipStream_t stream) {
    const float* x_phy = (const float*)d_in[0];   // (2000,1024,3) fp32
    const float* ps    = (const float*)d_in[1];   // (1024,288)    fp32
    float* out         = (float*)d_out;           // (2000,1024)   fp32

    // 256 blocks x 128 threads: per CU, wave0 = serial scan (critical path),
    // wave1 = FIR+reduce+store on an otherwise-idle SIMD.
    hbv_pc_kernel<<<256, 128, 0, stream>>>(x_phy, ps, out);
}

// Round 4
// 338.398 us; speedup vs baseline: 2.0028x; 1.1637x over previous
//
#include <hip/hip_runtime.h>

#define HBV_B    1024
#define HBV_NZ   1e-5f
#define LDSTR    64            // floats per step slot in LDS (one per lane)
#define BUFSZ    (15 * LDSTR)  // one 15-step chunk buffer

// ---------------------------------------------------------------------------
// Producer/consumer wave split; wall time = producer wave's serial 2000-step
// recurrence. This revision is chain surgery: the cross-step dependent chain
// is cut from ~22 VALU + 4 transcendentals to ~9 VALU + 4 transcendentals:
//   - SM2 = min(SM1, FC)                      (excess off-chain)
//   - capillary == C*SLZ*(1-SM2/FC) always    (C<=1, SM2<=FC => min redundant)
//     => SM3 = fma(SM2, c1, CSLZ), c1/CSLZ off-chain (SLZ_prev only)
//   - SM4 = max(SM3 - PET*ef, NZ)             (exact rewrite of min/sub/max)
//   - pow's in exponent domain with all muls folded into off-chain constants:
//       sw     = exp2(min(fma(BETA,  log2(SM),  -BETA*log2FC), 0))
//       PET*ef = exp2(min(fma(BETAET,log2(SM3),  cpet), log2PET))
//     cpet = log2PET - BETAET*log2(LP*FC); log2PET from forcing (off-chain).
// ---------------------------------------------------------------------------

struct F3 { float x, y, z; };   // 12B forcing record (P, T, PET)

// qr += lane-rotated qr within the 16-lane DPP row (row_ror:N = 0x120+N).
#define DPP_ADD_ROR(x, ctrl) do {                                              \
    int _r = __builtin_amdgcn_update_dpp(0, __float_as_int(x),                 \
                                         (ctrl), 0xF, 0xF, true);              \
    (x) += __int_as_float(_r);                                                 \
} while (0)

// ---- producer: one HBV state step; Qsim -> LDS ----------------------------
#define HBV_PSTEP(s, Pm, Tc, PETm, qdst) do {                                  \
    /* snow sub-recurrence: short parallel chain (forcing + snow states) */    \
    float rain = ((Tc) >= parTT) ? (Pm) : 0.0f;                                \
    float snow = (Pm) - rain;                                                  \
    SNOWPACK += snow;                                                          \
    float melt = fminf(fmaxf(__builtin_fmaf(parCFMAX, (Tc), negCT), 0.0f),     \
                       SNOWPACK);                                              \
    MELTWATER += melt; SNOWPACK -= melt;                                       \
    float refreeze = fminf(fmaxf(__builtin_fmaf(-CFRC, (Tc), CFRCTT), 0.0f),   \
                           MELTWATER);                                         \
    SNOWPACK += refreeze; MELTWATER -= refreeze;                               \
    float tosoil = fmaxf(__builtin_fmaf(-parCWH, SNOWPACK, MELTWATER), 0.0f);  \
    MELTWATER -= tosoil;                                                       \
    float rt = rain + tosoil;                                                  \
    /* off-chain helpers */                                                    \
    float lPET = __builtin_amdgcn_logf(PETm);      /* forcing-only */          \
    float cpet = lPET + nBEloglpfc;                                            \
    float CSLZ = parC * SLZ;                       /* SLZ_prev only */         \
    float c1   = __builtin_fmaf(-CSLZ, invFC, 1.0f);                           \
    float SMrt = SM + rt;                                                      \
    /* ---- the cross-step critical chain ---- */                              \
    float lSM = __builtin_amdgcn_logf(SM);                                     \
    float esw = fminf(__builtin_fmaf(parBETA, lSM, nBlogFC), 0.0f);            \
    float sw  = __builtin_amdgcn_exp2f(esw);                                   \
    float SM1 = __builtin_fmaf(-rt, sw, SMrt);                                 \
    float SM2 = fminf(SM1, parFC);                                             \
    float SM3 = __builtin_fmaf(SM2, c1, CSLZ);                                 \
    float lS3 = __builtin_amdgcn_logf(SM3);                                    \
    float eef = fminf(__builtin_fmaf(parBETAET, lS3, cpet), lPET);             \
    float PETef = __builtin_amdgcn_exp2f(eef);                                 \
    SM = fmaxf(SM3 - PETef, HBV_NZ);                                           \
    /* ---- off-chain: SUZ/SLZ/Q ---- */                                       \
    float recharge = rt * sw;                                                  \
    float excess   = SM1 - SM2;                                                \
    float capillary = SM3 - SM2;                                               \
    SUZ += recharge + excess;                                                  \
    float PERCa = fminf(SUZ, parPERC);                                         \
    SUZ -= PERCa;                                                              \
    float Q0 = parK0 * fmaxf(SUZ - parUZL, 0.0f);                              \
    SUZ -= Q0;                                                                 \
    float Q1 = parK1 * SUZ;                                                    \
    SUZ *= K1c;                                                                \
    SLZ = SLZ - capillary + PERCa;                                             \
    float Q2 = parK2 * SLZ;                                                    \
    SLZ *= K2c;                                                                \
    (qdst)[(s) * LDSTR] = Q0 + Q1 + Q2;                                        \
} while (0)

#define RUN15P(Pf, Tf, Ef, qdst) do {                                          \
    HBV_PSTEP( 0, (Pf)[ 0], (Tf)[ 0], (Ef)[ 0], qdst);                         \
    HBV_PSTEP( 1, (Pf)[ 1], (Tf)[ 1], (Ef)[ 1], qdst);                         \
    HBV_PSTEP( 2, (Pf)[ 2], (Tf)[ 2], (Ef)[ 2], qdst);                         \
    HBV_PSTEP( 3, (Pf)[ 3], (Tf)[ 3], (Ef)[ 3], qdst);                         \
    HBV_PSTEP( 4, (Pf)[ 4], (Tf)[ 4], (Ef)[ 4], qdst);                         \
    HBV_PSTEP( 5, (Pf)[ 5], (Tf)[ 5], (Ef)[ 5], qdst);                         \
    HBV_PSTEP( 6, (Pf)[ 6], (Tf)[ 6], (Ef)[ 6], qdst);                         \
    HBV_PSTEP( 7, (Pf)[ 7], (Tf)[ 7], (Ef)[ 7], qdst);                         \
    HBV_PSTEP( 8, (Pf)[ 8], (Tf)[ 8], (Ef)[ 8], qdst);                         \
    HBV_PSTEP( 9, (Pf)[ 9], (Tf)[ 9], (Ef)[ 9], qdst);                         \
    HBV_PSTEP(10, (Pf)[10], (Tf)[10], (Ef)[10], qdst);                         \
    HBV_PSTEP(11, (Pf)[11], (Tf)[11], (Ef)[11], qdst);                         \
    HBV_PSTEP(12, (Pf)[12], (Tf)[12], (Ef)[12], qdst);                         \
    HBV_PSTEP(13, (Pf)[13], (Tf)[13], (Ef)[13], qdst);                         \
    HBV_PSTEP(14, (Pf)[14], (Tf)[14], (Ef)[14], qdst);                         \
} while (0)

#define LOAD_CHUNK15(Pf, Tf, Ef, tbase) do {                                   \
    _Pragma("unroll")                                                          \
    for (int k_ = 0; k_ < 15; ++k_) {                                          \
        F3 _f = xb3[(size_t)((tbase) + k_) * HBV_B];                           \
        (Pf)[k_] = _f.x; (Tf)[k_] = _f.y; (Ef)[k_] = _f.z;                     \
    }                                                                          \
} while (0)

// ---- consumer: batched LDS reads -> 15-tap FIR ring -> DPP mean -> store ---
#define HBV_CSTEP(s, tb) do {                                                  \
    q[(s)] = qq[(s)];                                                          \
    float qr = 0.0f;                                                           \
    _Pragma("unroll")                                                          \
    for (int k_ = 0; k_ < 15; ++k_)                                            \
        qr += w[k_] * q[((s) - k_ + 15) % 15];                                 \
    DPP_ADD_ROR(qr, 0x128);                                                    \
    DPP_ADD_ROR(qr, 0x124);                                                    \
    DPP_ADD_ROR(qr, 0x122);                                                    \
    DPP_ADD_ROR(qr, 0x121);                                                    \
    if (m == 0) out[(size_t)((tb) + (s)) * HBV_B + b] = qr;                    \
} while (0)

#define CONS15(qsrc, tb) do {                                                  \
    float qq[15];                                                              \
    _Pragma("unroll")                                                          \
    for (int k_ = 0; k_ < 15; ++k_) qq[k_] = (qsrc)[k_ * LDSTR];               \
    HBV_CSTEP( 0, tb); HBV_CSTEP( 1, tb); HBV_CSTEP( 2, tb);                   \
    HBV_CSTEP( 3, tb); HBV_CSTEP( 4, tb); HBV_CSTEP( 5, tb);                   \
    HBV_CSTEP( 6, tb); HBV_CSTEP( 7, tb); HBV_CSTEP( 8, tb);                   \
    HBV_CSTEP( 9, tb); HBV_CSTEP(10, tb); HBV_CSTEP(11, tb);                   \
    HBV_CSTEP(12, tb); HBV_CSTEP(13, tb); HBV_CSTEP(14, tb);                   \
} while (0)

__global__ __launch_bounds__(128, 1)
void hbv_pc_kernel(const float* __restrict__ x_phy,   // (2000, 1024, 3)
                   const float* __restrict__ ps,      // (1024, 288)
                   float* __restrict__ out)           // (2000, 1024)
{
    const int lane = (int)threadIdx.x & 63;
    const int wave = (int)threadIdx.x >> 6;
    const int b = blockIdx.x * 4 + (lane >> 4);
    const int m = lane & 15;

    __shared__ float qbuf[2 * BUFSZ];   // 7.5 KB, double-buffered chunks

    const float* __restrict__ pb = ps + (size_t)b * 288;

    if (wave == 0) {
        // ------------------------- PRODUCER --------------------------------
        const float parBETA   = 1.0f   + pb[ 0*16 + m] * 5.0f;
        const float parFC     = 50.0f  + pb[ 1*16 + m] * 950.0f;
        const float parK0     = 0.05f  + pb[ 2*16 + m] * 0.85f;
        const float parK1     = 0.01f  + pb[ 3*16 + m] * 0.49f;
        const float parK2     = 0.001f + pb[ 4*16 + m] * 0.199f;
        const float parLP     = 0.2f   + pb[ 5*16 + m] * 0.8f;
        const float parPERC   =          pb[ 6*16 + m] * 10.0f;
        const float parUZL    =          pb[ 7*16 + m] * 100.0f;
        const float parTT     = -2.5f  + pb[ 8*16 + m] * 5.0f;
        const float parCFMAX  = 0.5f   + pb[ 9*16 + m] * 9.5f;
        const float parCFR    =          pb[10*16 + m] * 0.1f;
        const float parCWH    =          pb[11*16 + m] * 0.2f;
        const float parBETAET = 0.3f   + pb[12*16 + m] * 4.7f;
        const float parC      =          pb[13*16 + m];

        const float CFRC    = parCFR * parCFMAX;
        const float invFC   = 1.0f / parFC;
        const float negCT   = -parCFMAX * parTT;
        const float CFRCTT  =  CFRC * parTT;
        const float K1c     = 1.0f - parK1;
        const float K2c     = 1.0f - parK2;
        // exponent-domain constants
        const float nBlogFC    = -parBETA   * __builtin_amdgcn_logf(parFC);
        const float nBEloglpfc = -parBETAET * __builtin_amdgcn_logf(parLP * parFC);

        float SNOWPACK = HBV_NZ, MELTWATER = HBV_NZ, SM = HBV_NZ,
              SUZ = HBV_NZ, SLZ = HBV_NZ;

        const F3* __restrict__ xb3 = (const F3*)x_phy + b;
        float* const ql0 = &qbuf[lane];
        float* const ql1 = &qbuf[BUFSZ + lane];

        float Pa[15], Ta[15], Ea[15], Pb_[15], Tb_[15], Eb_[15];
        LOAD_CHUNK15(Pa, Ta, Ea, 0);

        // chunks 0..131 as pairs; prefetch next chunk during current's steps
#pragma unroll 1
        for (int jj = 0; jj < 66; ++jj) {
            LOAD_CHUNK15(Pb_, Tb_, Eb_, 15 * (2 * jj + 1));
            RUN15P(Pa, Ta, Ea, ql0);
            __syncthreads();                       // chunk 2jj ready
            LOAD_CHUNK15(Pa, Ta, Ea, 15 * (2 * jj + 2));   // jj=65 -> c132
            RUN15P(Pb_, Tb_, Eb_, ql1);
            __syncthreads();                       // chunk 2jj+1 ready
        }
        // epilogue: chunk 132 (in A) + 5-step tail chunk 133
        {
#pragma unroll
            for (int k = 0; k < 5; ++k) {
                F3 f = xb3[(size_t)(1995 + k) * HBV_B];
                Pb_[k] = f.x; Tb_[k] = f.y; Eb_[k] = f.z;
            }
            RUN15P(Pa, Ta, Ea, ql0);
            __syncthreads();                       // chunk 132 ready
            HBV_PSTEP(0, Pb_[0], Tb_[0], Eb_[0], ql1);
            HBV_PSTEP(1, Pb_[1], Tb_[1], Eb_[1], ql1);
            HBV_PSTEP(2, Pb_[2], Tb_[2], Eb_[2], ql1);
            HBV_PSTEP(3, Pb_[3], Tb_[3], Eb_[3], ql1);
            HBV_PSTEP(4, Pb_[4], Tb_[4], Eb_[4], ql1);
            __syncthreads();                       // tail ready
        }
    } else {
        // ------------------------- CONSUMER --------------------------------
        const float rout_a = pb[256 + m]      * 2.9f;
        const float rout_b = pb[256 + 16 + m] * 6.5f;

        // w[k] ∝ t_k^(a-1) * exp(-t_k/theta); Gamma/theta^a factor cancels
        // under normalization. Pre-scaled by 1/16 to fold in the mean over m.
        const float aa    = fmaxf(rout_a, 0.0f) + 0.1f;
        const float theta = fmaxf(rout_b, 0.0f) + 0.5f;
        const float am1   = aa - 1.0f;
        const float nit   = -1.4426950408889634f / theta;
        float w[15];
        float wsum = 0.0f;
#pragma unroll
        for (int k = 0; k < 15; ++k) {
            float tk = (float)k + 0.5f;
            float e  = am1 * __builtin_amdgcn_logf(tk) + nit * tk;
            w[k] = __builtin_amdgcn_exp2f(e);
            wsum += w[k];
        }
        const float wscale = 1.0f / (16.0f * wsum);
#pragma unroll
        for (int k = 0; k < 15; ++k) w[k] *= wscale;

        float q[15];
#pragma unroll
        for (int k = 0; k < 15; ++k) q[k] = 0.0f;

        const float* const qr0 = &qbuf[lane];
        const float* const qr1 = &qbuf[BUFSZ + lane];

#pragma unroll 1
        for (int jj = 0; jj < 66; ++jj) {
            __syncthreads();
            CONS15(qr0, 30 * jj);
            __syncthreads();
            CONS15(qr1, 30 * jj + 15);
        }
        __syncthreads();
        CONS15(qr0, 1980);
        __syncthreads();
        {   // 5-step tail from buffer 1
            float qq[5];
#pragma unroll
            for (int k = 0; k < 5; ++k) qq[k] = qr1[k * LDSTR];
            HBV_CSTEP(0, 1995);
            HBV_CSTEP(1, 1995);
            HBV_CSTEP(2, 1995);
            HBV_CSTEP(3, 1995);
            HBV_CSTEP(4, 1995);
        }
    }
}

extern "C" void kernel_launch(void* const* d_in, const int* in_sizes, int n_in,
                              void* d_out, int out_size, void* d_ws, size_t ws_size,
                              hipStream_t stream) {
    const float* x_phy = (const float*)d_in[0];   // (2000,1024,3) fp32
    const float* ps    = (const float*)d_in[1];   // (1024,288)    fp32
    float* out         = (float*)d_out;           // (2000,1024)   fp32

    // 256 blocks x 128 threads: per CU, wave0 = serial scan (critical path),
    // wave1 = FIR+reduce+store. Wall time = producer chain latency x 2000.
    hbv_pc_kernel<<<256, 128, 0, stream>>>(x_phy, ps, out);
}

// Round 5
// 325.171 us; speedup vs baseline: 2.0843x; 1.0407x over previous
//
#include <hip/hip_runtime.h>

#define HBV_B    1024
#define HBV_NZ   1e-5f
#define LDSTR    64            // floats per step slot (one per lane)
#define BUFSZ    (15 * LDSTR)  // one 15-step chunk buffer

// ---------------------------------------------------------------------------
// 3-stage pipeline over 2 waves (one block = 128 threads on one CU):
//   wave 1 (stage A, snow):  SNOWPACK/MELTWATER recurrence — depends ONLY on
//           forcing, no back-edge from soil — ships rt + log2(PET) via LDS,
//           one chunk AHEAD of the soil wave.  Also stage C (routing): 15-tap
//           FIR + DPP mean + store, one chunk BEHIND the soil wave.
//   wave 0 (stage B, soil):  the coupled SM/SLZ/SUZ core only. Its SM
//           self-loop (log2->fma->min->exp2->fma->min->fma->log2->fma->min->
//           exp2->sub->max = 13 ops, 4 transcendentals) is the structural
//           critical path of the whole problem; everything else is stripped
//           off this wave so in-order issue pays nothing extra.
// Phase p: wave0 does soil chunk p-1; wave1 does snow chunk p + route p-2.
// 135 barriers each. rt/lp/q double-buffered by chunk parity:
//   snow c -> rt[c&1] at phase c;   soil c reads rt[c&1] at phase c+1. OK
//   soil c -> q[c&1]  at phase c+1; route c reads q[c&1] at phase c+2. OK
// ---------------------------------------------------------------------------

struct F3 { float x, y, z; };   // 12B forcing record (P, T, PET)

// x += lane-rotated x within the 16-lane DPP row (row_ror:N = 0x120+N).
#define DPP_ADD_ROR(x, ctrl) do {                                              \
    int _r = __builtin_amdgcn_update_dpp(0, __float_as_int(x),                 \
                                         (ctrl), 0xF, 0xF, true);              \
    (x) += __int_as_float(_r);                                                 \
} while (0)

// ---- stage B: soil step (critical wave). rr/lpv pre-read from LDS. --------
#define SOIL_STEP(s, rt_, lPET_, qdst) do {                                    \
    float rt   = (rt_);                                                        \
    float lPET = (lPET_);                                                      \
    /* off-chain helpers */                                                    \
    float cpet = lPET + nBEloglpfc;                                            \
    float CSLZ = parC * SLZ;                                                   \
    float c1   = __builtin_fmaf(-CSLZ, invFC, 1.0f);                           \
    float SMrt = SM + rt;                                                      \
    /* ---- cross-step critical chain (4 trans + 9 VALU) ---- */               \
    float lSM = __builtin_amdgcn_logf(SM);                                     \
    float esw = fminf(__builtin_fmaf(parBETA, lSM, nBlogFC), 0.0f);            \
    float sw  = __builtin_amdgcn_exp2f(esw);                                   \
    float SM1 = __builtin_fmaf(-rt, sw, SMrt);                                 \
    float SM2 = fminf(SM1, parFC);                                             \
    float SM3 = __builtin_fmaf(SM2, c1, CSLZ);                                 \
    float lS3 = __builtin_amdgcn_logf(SM3);                                    \
    float eef = fminf(__builtin_fmaf(parBETAET, lS3, cpet), lPET);             \
    float PETef = __builtin_amdgcn_exp2f(eef);                                 \
    SM = fmaxf(SM3 - PETef, HBV_NZ);                                           \
    /* ---- off-chain: SUZ/SLZ/Q ---- */                                       \
    float recharge  = rt * sw;                                                 \
    float excess    = SM1 - SM2;                                               \
    float capillary = SM3 - SM2;                                               \
    SUZ += recharge + excess;                                                  \
    float PERCa = fminf(SUZ, parPERC);                                         \
    SUZ -= PERCa;                                                              \
    float Q0 = parK0 * fmaxf(SUZ - parUZL, 0.0f);                              \
    SUZ -= Q0;                                                                 \
    float Q1 = parK1 * SUZ;                                                    \
    SUZ *= K1c;                                                                \
    SLZ = SLZ - capillary + PERCa;                                             \
    float Q2 = parK2 * SLZ;                                                    \
    SLZ *= K2c;                                                                \
    (qdst)[(s) * LDSTR] = Q0 + Q1 + Q2;                                        \
} while (0)

#define SOIL_CHUNK(nsteps, rts, lps, qds) do {                                 \
    float rr[15], lpv[15];                                                     \
    _Pragma("unroll")                                                          \
    for (int k_ = 0; k_ < (nsteps); ++k_) {                                    \
        rr[k_]  = (rts)[k_ * LDSTR];                                           \
        lpv[k_] = (lps)[k_ * LDSTR];                                           \
    }                                                                          \
    _Pragma("unroll")                                                          \
    for (int s_ = 0; s_ < (nsteps); ++s_)                                      \
        SOIL_STEP(s_, rr[s_], lpv[s_], qds);                                   \
} while (0)

// ---- stage A: snow step (forcing-only recurrence) -> rt, lPET to LDS ------
#define SNOW_STEP(s, Pm, Tc, PETm, rts, lps) do {                              \
    float rain = ((Tc) >= parTT) ? (Pm) : 0.0f;                                \
    float snow = (Pm) - rain;                                                  \
    SNOW += snow;                                                              \
    float melt = fminf(fmaxf(__builtin_fmaf(parCFMAX, (Tc), negCT), 0.0f),     \
                       SNOW);                                                  \
    MELT += melt; SNOW -= melt;                                                \
    float refreeze = fminf(fmaxf(__builtin_fmaf(-CFRC, (Tc), CFRCTT), 0.0f),   \
                           MELT);                                              \
    SNOW += refreeze; MELT -= refreeze;                                        \
    float tosoil = fmaxf(__builtin_fmaf(-parCWH, SNOW, MELT), 0.0f);           \
    MELT -= tosoil;                                                            \
    (rts)[(s) * LDSTR] = rain + tosoil;                                        \
    (lps)[(s) * LDSTR] = __builtin_amdgcn_logf(PETm);                          \
} while (0)

#define SNOW_CHUNK(nsteps, Pf, Tf, Ef, rts, lps) do {                          \
    _Pragma("unroll")                                                          \
    for (int s_ = 0; s_ < (nsteps); ++s_)                                      \
        SNOW_STEP(s_, (Pf)[s_], (Tf)[s_], (Ef)[s_], rts, lps);                 \
} while (0)

#define LOAD_CHUNK(nsteps, Pf, Tf, Ef, tbase) do {                             \
    _Pragma("unroll")                                                          \
    for (int k_ = 0; k_ < (nsteps); ++k_) {                                    \
        F3 _f = xb3[(size_t)((tbase) + k_) * HBV_B];                           \
        (Pf)[k_] = _f.x; (Tf)[k_] = _f.y; (Ef)[k_] = _f.z;                     \
    }                                                                          \
} while (0)

// ---- stage C: routing. Chunk bases are multiples of 15 -> ring slot == s. -
#define ROUTE_STEP(s, tb) do {                                                 \
    q[(s)] = qq[(s)];                                                          \
    float qr = 0.0f;                                                           \
    _Pragma("unroll")                                                          \
    for (int k_ = 0; k_ < 15; ++k_)                                            \
        qr += w[k_] * q[((s) - k_ + 15) % 15];                                 \
    DPP_ADD_ROR(qr, 0x128);                                                    \
    DPP_ADD_ROR(qr, 0x124);                                                    \
    DPP_ADD_ROR(qr, 0x122);                                                    \
    DPP_ADD_ROR(qr, 0x121);                                                    \
    if (m == 0) out[(size_t)((tb) + (s)) * HBV_B + b] = qr;                    \
} while (0)

#define ROUTE_CHUNK(nsteps, qsrc, tb) do {                                     \
    float qq[15];                                                              \
    _Pragma("unroll")                                                          \
    for (int k_ = 0; k_ < (nsteps); ++k_) qq[k_] = (qsrc)[k_ * LDSTR];         \
    _Pragma("unroll")                                                          \
    for (int s_ = 0; s_ < (nsteps); ++s_) ROUTE_STEP(s_, tb);                  \
} while (0)

__global__ __launch_bounds__(128, 1)
void hbv_pipe3_kernel(const float* __restrict__ x_phy,   // (2000, 1024, 3)
                      const float* __restrict__ ps,      // (1024, 288)
                      float* __restrict__ out)           // (2000, 1024)
{
    const int lane = (int)threadIdx.x & 63;
    const int wave = (int)threadIdx.x >> 6;
    const int b = blockIdx.x * 4 + (lane >> 4);
    const int m = lane & 15;

    __shared__ float qbuf [2 * BUFSZ];   // Qsim chunks   (soil -> route)
    __shared__ float rtbuf[2 * BUFSZ];   // rain+tosoil   (snow -> soil)
    __shared__ float lpbuf[2 * BUFSZ];   // log2(PET)     (snow -> soil)

    const float* __restrict__ pb = ps + (size_t)b * 288;

    if (wave == 0) {
        // ---------------- stage B: soil (critical wave) --------------------
        const float parBETA   = 1.0f   + pb[ 0*16 + m] * 5.0f;
        const float parFC     = 50.0f  + pb[ 1*16 + m] * 950.0f;
        const float parK0     = 0.05f  + pb[ 2*16 + m] * 0.85f;
        const float parK1     = 0.01f  + pb[ 3*16 + m] * 0.49f;
        const float parK2     = 0.001f + pb[ 4*16 + m] * 0.199f;
        const float parLP     = 0.2f   + pb[ 5*16 + m] * 0.8f;
        const float parPERC   =          pb[ 6*16 + m] * 10.0f;
        const float parUZL    =          pb[ 7*16 + m] * 100.0f;
        const float parBETAET = 0.3f   + pb[12*16 + m] * 4.7f;
        const float parC      =          pb[13*16 + m];

        const float invFC   = 1.0f / parFC;
        const float K1c     = 1.0f - parK1;
        const float K2c     = 1.0f - parK2;
        const float nBlogFC    = -parBETA   * __builtin_amdgcn_logf(parFC);
        const float nBEloglpfc = -parBETAET * __builtin_amdgcn_logf(parLP * parFC);

        float SM = HBV_NZ, SUZ = HBV_NZ, SLZ = HBV_NZ;

        float* const qb0 = &qbuf [lane];
        float* const qb1 = &qbuf [BUFSZ + lane];
        const float* const rb0 = &rtbuf[lane];
        const float* const rb1 = &rtbuf[BUFSZ + lane];
        const float* const lb0 = &lpbuf[lane];
        const float* const lb1 = &lpbuf[BUFSZ + lane];

        __syncthreads();                                   // p=0 (snow c0)
#pragma unroll 1
        for (int jj = 0; jj < 66; ++jj) {                  // chunks 0..131
            SOIL_CHUNK(15, rb0, lb0, qb0); __syncthreads();
            SOIL_CHUNK(15, rb1, lb1, qb1); __syncthreads();
        }
        SOIL_CHUNK(15, rb0, lb0, qb0); __syncthreads();    // chunk 132
        SOIL_CHUNK( 5, rb1, lb1, qb1); __syncthreads();    // chunk 133 (tail)
        // 135 barriers total.
    } else {
        // ------------- stages A + C: snow (ahead) + routing (behind) -------
        const float parTT     = -2.5f  + pb[ 8*16 + m] * 5.0f;
        const float parCFMAX  = 0.5f   + pb[ 9*16 + m] * 9.5f;
        const float parCFR    =          pb[10*16 + m] * 0.1f;
        const float parCWH    =          pb[11*16 + m] * 0.2f;
        const float rout_a    =          pb[256 + m]      * 2.9f;
        const float rout_b    =          pb[256 + 16 + m] * 6.5f;

        const float CFRC   = parCFR * parCFMAX;
        const float negCT  = -parCFMAX * parTT;
        const float CFRCTT =  CFRC * parTT;

        // w[k] ∝ t_k^(a-1) exp(-t_k/theta); Gamma/theta^a cancels under the
        // normalization. Pre-scaled by 1/16 to fold in the mean over m.
        const float aa    = fmaxf(rout_a, 0.0f) + 0.1f;
        const float theta = fmaxf(rout_b, 0.0f) + 0.5f;
        const float am1   = aa - 1.0f;
        const float nit   = -1.4426950408889634f / theta;
        float w[15];
        float wsum = 0.0f;
#pragma unroll
        for (int k = 0; k < 15; ++k) {
            float tk = (float)k + 0.5f;
            float e  = am1 * __builtin_amdgcn_logf(tk) + nit * tk;
            w[k] = __builtin_amdgcn_exp2f(e);
            wsum += w[k];
        }
        const float wscale = 1.0f / (16.0f * wsum);
#pragma unroll
        for (int k = 0; k < 15; ++k) w[k] *= wscale;

        float q[15];
#pragma unroll
        for (int k = 0; k < 15; ++k) q[k] = 0.0f;

        float SNOW = HBV_NZ, MELT = HBV_NZ;

        float* const rb0 = &rtbuf[lane];
        float* const rb1 = &rtbuf[BUFSZ + lane];
        float* const lb0 = &lpbuf[lane];
        float* const lb1 = &lpbuf[BUFSZ + lane];
        const float* const qb0 = &qbuf[lane];
        const float* const qb1 = &qbuf[BUFSZ + lane];

        const F3* __restrict__ xb3 = (const F3*)x_phy + b;
        float PA[15], TA[15], EA[15], PB[15], TB[15], EB[15];

        LOAD_CHUNK(15, PA, TA, EA, 0);
        // p=0: snow c0 -> rt0; prefetch c1
        SNOW_CHUNK(15, PA, TA, EA, rb0, lb0);
        LOAD_CHUNK(15, PB, TB, EB, 15);
        __syncthreads();
        // p=1: snow c1 -> rt1; prefetch c2
        SNOW_CHUNK(15, PB, TB, EB, rb1, lb1);
        LOAD_CHUNK(15, PA, TA, EA, 30);
        __syncthreads();
        // p=2..131 (65 double-phases): snow c=p, prefetch c=p+1, route c=p-2
#pragma unroll 1
        for (int jj = 1; jj <= 65; ++jj) {
            SNOW_CHUNK(15, PA, TA, EA, rb0, lb0);          // chunk 2jj (even)
            LOAD_CHUNK(15, PB, TB, EB, 15 * (2 * jj + 1));
            ROUTE_CHUNK(15, qb0, 15 * (2 * jj - 2));       // chunk 2jj-2
            __syncthreads();
            SNOW_CHUNK(15, PB, TB, EB, rb1, lb1);          // chunk 2jj+1
            LOAD_CHUNK(15, PA, TA, EA, 15 * (2 * jj + 2));
            ROUTE_CHUNK(15, qb1, 15 * (2 * jj - 1));       // chunk 2jj-1
            __syncthreads();
        }
        // p=132: snow c132 -> rt0; prefetch tail (5); route c130
        SNOW_CHUNK(15, PA, TA, EA, rb0, lb0);
        LOAD_CHUNK(5, PB, TB, EB, 1995);
        ROUTE_CHUNK(15, qb0, 1950);
        __syncthreads();
        // p=133: snow tail c133 (5) -> rt1; route c131
        SNOW_CHUNK(5, PB, TB, EB, rb1, lb1);
        ROUTE_CHUNK(15, qb1, 1965);
        __syncthreads();
        // p=134: route c132
        ROUTE_CHUNK(15, qb0, 1980);
        __syncthreads();
        // p=135: route tail c133 (5)
        ROUTE_CHUNK(5, qb1, 1995);
        // 135 barriers total (2 + 130 + 2 + 1).
    }
}

extern "C" void kernel_launch(void* const* d_in, const int* in_sizes, int n_in,
                              void* d_out, int out_size, void* d_ws, size_t ws_size,
                              hipStream_t stream) {
    const float* x_phy = (const float*)d_in[0];   // (2000,1024,3) fp32
    const float* ps    = (const float*)d_in[1];   // (1024,288)    fp32
    float* out         = (float*)d_out;           // (2000,1024)   fp32

    // 256 blocks x 128 threads. Wall time = soil wave's SM-chain latency
    // (4 transcendentals + 9 VALU per step) x 2000 steps.
    hbv_pipe3_kernel<<<256, 128, 0, stream>>>(x_phy, ps, out);
}